// Round 4
// baseline (3946.970 us; speedup 1.0000x reference)
//
#include <hip/hip_runtime.h>

// Stacked LSTM B=2048,T=512,IN=4,H=64,L=4,OUT=5 — cross-layer pipelined MFMA.
// PLAIN launch, 512 blocks: layer = blockIdx&3, batch group = blockIdx>>2
// (16 batches/group). Co-residency by construction: __launch_bounds__(256,2)
// (VGPR<=256) + 18.4KB LDS guarantee 2 blocks/CU, grid = 2*256 CUs exactly,
// so all blocks are resident and inter-block spin-waits always progress.
// (R3's hipLaunchCooperativeKernel failed to launch -> all-zeros output.)
// Layer l step t depends only on layer l-1 step t: all 4 layers run with a
// ~CHK-step skew (2048 serial steps -> ~536) and 2 blocks/CU hide each
// other's latency. Inter-layer h flows through a global ring (RING=32 steps,
// L2/L3-resident) with per-(boundary,group) release/acquire flags in d_ws.
// Math per layer: 16x16x32 bf16 MFMA, hi/lo fp32 split (3 MFMAs, ~2^-18 rel),
// weights register-resident as B-frags, pointwise fully in registers, aBuf
// double-buffered (1 barrier/step). Layer 0's K=4 input folded into MFMA via
// zero-padded K-tile. FC fused into layer 3.

#define B_    2048
#define T_    512
#define H_    64
#define NB    16
#define OUT_  5
#define CHK   8
#define RING  32
#define NGRP  128   // B_/NB

typedef __attribute__((ext_vector_type(8))) short bf16x8;
typedef __attribute__((ext_vector_type(4))) float f32x4;

__device__ __forceinline__ float sigf(float x) {
    return __builtin_amdgcn_rcpf(1.0f + __expf(-x));
}
__device__ __forceinline__ float tanh_fast(float x) {
    return 1.0f - 2.0f * __builtin_amdgcn_rcpf(1.0f + __expf(2.0f * x));
}
__device__ __forceinline__ unsigned short f2bf(float x) {
    unsigned u = __float_as_uint(x);
    u += 0x7fffu + ((u >> 16) & 1u);
    return (unsigned short)(u >> 16);
}
__device__ __forceinline__ float bf2f(unsigned short b) {
    return __uint_as_float(((unsigned)b) << 16);
}

__global__ void zero_flags_k(unsigned int* flags, int n) {
    int i = blockIdx.x * 256 + threadIdx.x;
    if (i < n) flags[i] = 0;
}

__global__ __launch_bounds__(256, 2) void lstm_pipe_k(
    const float* __restrict__ x,      // [B,T,4]
    const float* __restrict__ W_ih0,  // [256,4]
    const float* __restrict__ W_ihr,  // [3,256,64]
    const float* __restrict__ W_hh,   // [4,256,64]
    const float* __restrict__ b_ih,   // [4,256]
    const float* __restrict__ b_hh,   // [4,256]
    const float* __restrict__ W_fc,   // [5,64]
    const float* __restrict__ b_fc,   // [5]
    float* __restrict__ out,          // [B,5]
    float* __restrict__ ring,         // [3][RING][B][H]
    unsigned int* __restrict__ flags) // prod[4][NGRP], cons[4][NGRP]
{
    const int layer = blockIdx.x & 3;
    const int grp   = blockIdx.x >> 2;
    const int b0    = grp * NB;
    const int tid   = threadIdx.x;
    const int lane  = tid & 63;
    const int wv    = tid >> 6;
    const int q     = lane >> 4;
    const int ln    = lane & 15;
    const int u     = wv * 16 + ln;   // gate-column / hidden unit owned by lane

    // [pingpong][hilo][k-octet][m][j]  -> 16 KB
    __shared__ unsigned short aBuf[2][2][16][16][8];
    __shared__ float xc[CHK][NB][4];  // layer-0 x chunk staging

    // zero aBuf once (layer 0 relies on zero-padded octets; ordered by the
    // first chunk-start __syncthreads below)
    for (int i = tid; i < 2 * 2 * 16 * 16 * 8; i += 256)
        ((unsigned short*)aBuf)[i] = 0;

    unsigned int* prodSelf = flags + layer * NGRP + grp;             // layer<3 writes
    unsigned int* prodPrev = flags + (layer - 1) * NGRP + grp;       // layer>0 waits
    unsigned int* consSelf = flags + (4 + layer) * NGRP + grp;       // layer<3 waits
    unsigned int* consPrev = flags + (4 + layer - 1) * NGRP + grp;   // layer>0 writes

    const float* ringPrev = ring + (size_t)(layer - 1) * RING * B_ * H_;
    float*       ringSelf = ring + (size_t)layer * RING * B_ * H_;

    // ---- weights -> B-fragments (hi/lo) in registers ----
    const float* Wih = (layer == 0) ? W_ih0 : (W_ihr + (size_t)(layer - 1) * 256 * 64);
    const float* Whh = W_hh + (size_t)layer * 256 * 64;

    bf16x8 Bh[4][4], Bl[4][4];
#pragma unroll
    for (int nti = 0; nti < 4; ++nti) {
        const int n = nti * 64 + u;
#pragma unroll
        for (int kt = 0; kt < 4; ++kt) {
            const int k = kt * 32 + q * 8;
            float vv[8];
            if (k < 64) {
                float4 v0 = *(const float4*)(Whh + n * 64 + k);
                float4 v1 = *(const float4*)(Whh + n * 64 + k + 4);
                vv[0] = v0.x; vv[1] = v0.y; vv[2] = v0.z; vv[3] = v0.w;
                vv[4] = v1.x; vv[5] = v1.y; vv[6] = v1.z; vv[7] = v1.w;
            } else if (layer == 0) {
#pragma unroll
                for (int j = 0; j < 8; ++j) {
                    const int kk = k - 64 + j;            // index into IN=4
                    vv[j] = (kk < 4) ? Wih[n * 4 + kk] : 0.0f;
                }
            } else {
                float4 v0 = *(const float4*)(Wih + n * 64 + (k - 64));
                float4 v1 = *(const float4*)(Wih + n * 64 + (k - 64) + 4);
                vv[0] = v0.x; vv[1] = v0.y; vv[2] = v0.z; vv[3] = v0.w;
                vv[4] = v1.x; vv[5] = v1.y; vv[6] = v1.z; vv[7] = v1.w;
            }
            bf16x8 fh, fl;
#pragma unroll
            for (int j = 0; j < 8; ++j) {
                unsigned short hb = f2bf(vv[j]);
                fh[j] = (short)hb;
                fl[j] = (short)f2bf(vv[j] - bf2f(hb));
            }
            Bh[nti][kt] = fh;
            Bl[nti][kt] = fl;
        }
    }

    float bias[4];
#pragma unroll
    for (int nti = 0; nti < 4; ++nti)
        bias[nti] = b_ih[layer * 256 + nti * 64 + u] + b_hh[layer * 256 + nti * 64 + u];

    const int rb = tid >> 4, cb = tid & 15;   // mid-layer ring-read mapping
    float c[4] = {0.f, 0.f, 0.f, 0.f};
    float h[4] = {0.f, 0.f, 0.f, 0.f};

    for (int t0 = 0; t0 < T_; t0 += CHK) {
        // ---- chunk-start sync (tid 0 spins; guard turns a deadlock into a
        // visible wrong answer instead of a bench timeout) ----
        if (tid == 0) {
            if (layer > 0) {
                unsigned guard = 0;
                while (__hip_atomic_load(prodPrev, __ATOMIC_ACQUIRE,
                                         __HIP_MEMORY_SCOPE_AGENT) < (unsigned)(t0 + CHK)) {
                    __builtin_amdgcn_s_sleep(2);
                    if (++guard > (1u << 25)) break;
                }
            }
            if (layer < 3 && t0 + CHK > RING) {
                unsigned guard = 0;
                while (__hip_atomic_load(consSelf, __ATOMIC_ACQUIRE,
                                         __HIP_MEMORY_SCOPE_AGENT) < (unsigned)(t0 + CHK - RING)) {
                    __builtin_amdgcn_s_sleep(2);
                    if (++guard > (1u << 25)) break;
                }
            }
        }
        __syncthreads();

        // ---- chunk input loads ----
        float4 pf[CHK];
        if (layer == 0) {
            if (tid < 128) {
                const int m = tid >> 3, j = tid & 7;
                *(float4*)&xc[j][m][0] =
                    *(const float4*)(x + (size_t)(b0 + m) * (T_ * 4) + (t0 + j) * 4);
            }
            __syncthreads();   // xc visible before step staging
        } else {
#pragma unroll
            for (int j = 0; j < CHK; ++j)
                pf[j] = *(const float4*)(ringPrev +
                         ((size_t)((t0 + j) & (RING - 1)) * B_ + (b0 + rb)) * H_ + cb * 4);
        }

        // ---- CHK steps ----
#pragma unroll
        for (int tt = 0; tt < CHK; ++tt) {
            const int t = t0 + tt;
            const int p = t & 1;

            // stage h(t-1) into octets 0..7 of aBuf[p]
#pragma unroll
            for (int r = 0; r < 4; ++r) {
                const int m = q * 4 + r;
                unsigned short hb = f2bf(h[r]);
                aBuf[p][0][u >> 3][m][u & 7] = hb;
                aBuf[p][1][u >> 3][m][u & 7] = f2bf(h[r] - bf2f(hb));
            }
            // stage input into octets 8..15
            if (layer == 0) {
                if (tid < 64) {
                    const int m = tid >> 2, e = tid & 3;
                    const float v = xc[tt][m][e];
                    unsigned short hb = f2bf(v);
                    aBuf[p][0][8][m][e] = hb;
                    aBuf[p][1][8][m][e] = f2bf(v - bf2f(hb));
                }
            } else {
                const float4 v = pf[tt];
                ushort4 hv, lv;
                hv.x = f2bf(v.x); lv.x = f2bf(v.x - bf2f(hv.x));
                hv.y = f2bf(v.y); lv.y = f2bf(v.y - bf2f(hv.y));
                hv.z = f2bf(v.z); lv.z = f2bf(v.z - bf2f(hv.z));
                hv.w = f2bf(v.w); lv.w = f2bf(v.w - bf2f(hv.w));
                const int oct = 8 + (cb >> 1), jj = (cb & 1) * 4;
                *(ushort4*)&aBuf[p][0][oct][rb][jj] = hv;
                *(ushort4*)&aBuf[p][1][oct][rb][jj] = lv;
            }
            __syncthreads();   // the ONLY per-step barrier (double-buffered aBuf)

            // A fragments
            bf16x8 Ah[4], Al[4];
#pragma unroll
            for (int kt = 0; kt < 4; ++kt) {
                Ah[kt] = *(const bf16x8*)&aBuf[p][0][kt * 4 + q][ln][0];
                Al[kt] = *(const bf16x8*)&aBuf[p][1][kt * 4 + q][ln][0];
            }

            f32x4 acc[4];
#pragma unroll
            for (int nti = 0; nti < 4; ++nti) acc[nti] = (f32x4){0.f, 0.f, 0.f, 0.f};
#pragma unroll
            for (int kt = 0; kt < 4; ++kt) {
#pragma unroll
                for (int nti = 0; nti < 4; ++nti) {
                    acc[nti] = __builtin_amdgcn_mfma_f32_16x16x32_bf16(Ah[kt], Bh[nti][kt], acc[nti], 0, 0, 0);
                    acc[nti] = __builtin_amdgcn_mfma_f32_16x16x32_bf16(Al[kt], Bh[nti][kt], acc[nti], 0, 0, 0);
                    acc[nti] = __builtin_amdgcn_mfma_f32_16x16x32_bf16(Ah[kt], Bl[nti][kt], acc[nti], 0, 0, 0);
                }
            }

            // pointwise in registers; write h to own ring
#pragma unroll
            for (int r = 0; r < 4; ++r) {
                const int m = q * 4 + r;
                const float gi = acc[0][r] + bias[0];
                const float gf = acc[1][r] + bias[1];
                const float gg = acc[2][r] + bias[2];
                const float go = acc[3][r] + bias[3];
                c[r] = sigf(gf) * c[r] + sigf(gi) * tanh_fast(gg);
                h[r] = sigf(go) * tanh_fast(c[r]);
                if (layer < 3)
                    ringSelf[((size_t)(t & (RING - 1)) * B_ + (b0 + m)) * H_ + u] = h[r];
            }
        }

        // ---- chunk-end publish (barrier drains all waves' ring stores) ----
        __syncthreads();
        if (tid == 0) {
            const unsigned done = (unsigned)(t0 + CHK);
            if (layer < 3) {
                __threadfence();
                __hip_atomic_store(prodSelf, done, __ATOMIC_RELEASE, __HIP_MEMORY_SCOPE_AGENT);
            }
            if (layer > 0)
                __hip_atomic_store(consPrev, done, __ATOMIC_RELEASE, __HIP_MEMORY_SCOPE_AGENT);
        }
    }

    // ---- FC epilogue (layer 3 only) ----
    if (layer == 3) {
        __syncthreads();
        float* hf = (float*)&aBuf[0][0][0][0][0];   // 16x64 f32 scratch
#pragma unroll
        for (int r = 0; r < 4; ++r) hf[(q * 4 + r) * H_ + u] = h[r];
        __syncthreads();
        if (tid < NB * OUT_) {
            const int b = tid / OUT_, o = tid % OUT_;
            float a = b_fc[o];
#pragma unroll
            for (int k = 0; k < H_; ++k)
                a = fmaf(hf[b * H_ + k], W_fc[o * H_ + k], a);
            out[(b0 + b) * OUT_ + o] = a;
        }
    }
}

extern "C" void kernel_launch(void* const* d_in, const int* in_sizes, int n_in,
                              void* d_out, int out_size, void* d_ws, size_t ws_size,
                              hipStream_t stream) {
    const float* x     = (const float*)d_in[0];
    const float* W_ih0 = (const float*)d_in[1];
    const float* W_ihr = (const float*)d_in[2];
    const float* W_hh  = (const float*)d_in[3];
    const float* b_ih  = (const float*)d_in[4];
    const float* b_hh  = (const float*)d_in[5];
    const float* W_fc  = (const float*)d_in[6];
    const float* b_fc  = (const float*)d_in[7];
    float* out = (float*)d_out;

    float* ring = (float*)d_ws;                                        // 3*32*2048*64*4 = 50.3 MB
    unsigned int* flags = (unsigned int*)((char*)d_ws + (64u << 20));  // 8*NGRP uints

    zero_flags_k<<<dim3(4), dim3(256), 0, stream>>>(flags, 8 * NGRP);

    lstm_pipe_k<<<dim3(4 * NGRP), dim3(256), 0, stream>>>(
        x, W_ih0, W_ihr, W_hh, b_ih, b_hh, W_fc, b_fc, out, ring, flags);
}

// Round 5
// 1282.553 us; speedup vs baseline: 3.0774x; 3.0774x over previous
//
#include <hip/hip_runtime.h>

// Stacked LSTM B=2048,T=512,IN=4,H=64,L=4,OUT=5 — single-block layer pipeline.
// ONE kernel, grid 128, block 512 (8 waves). Wave pair (2l, 2l+1) = layer l;
// all 4 layers of a 16-batch group run in the SAME block with 1-step skew
// (iteration i: layer l processes t = i-l). Inter-layer h flows through LDS
// (double-buffered by step parity) with ONE __syncthreads per iteration —
// no global ring, no flags, no fences (R4's cross-block pipeline died on
// cross-XCD coherence: fences forced ring through HBM, 3947us > sequential).
// Critical path: 2048 serial steps -> T+3 = 515 iterations.
// Math: 16x16x32 FP16 MFMA. Weights single-plane f16 in registers (f16 has
// 11-bit mantissa; |W|<=0.6 so no overflow; preact err ~3e-4 << 2.5e-3 thr).
// Activations hi/lo f16 split (2 MFMAs: Ah*W + Al*W). A-operand LDS layout
// K-permuted (phi(u)=4*(u&15)+(u>>4)) so each lane's 2 h values are column-
// adjacent -> f16x2 staging writes; weights column-permuted to match.
// Wave j of layer l owns gate tiles {g*4+2j+s}: lane has all 4 gates of
// units u=(2j+s)*16+ln -> pointwise fully in registers. FC fused at end.

#define B_    2048
#define T_    512
#define H_    64
#define NB    16
#define OUT_  5
#define ROWE  140      // f16 elems per A-row (280B: 8B-aligned, bank-staggered)

typedef _Float16 f16;
typedef __attribute__((ext_vector_type(8))) _Float16 f16x8;
typedef __attribute__((ext_vector_type(2))) _Float16 f16x2;
typedef __attribute__((ext_vector_type(4))) float f32x4;

__device__ __forceinline__ float sigf(float x) {
    return __builtin_amdgcn_rcpf(1.0f + __expf(-x));
}
__device__ __forceinline__ float tanh_fast(float x) {
    return 1.0f - 2.0f * __builtin_amdgcn_rcpf(1.0f + __expf(2.0f * x));
}

__global__ __launch_bounds__(512, 2) void lstm_fused_k(
    const float* __restrict__ x,      // [B,T,4]
    const float* __restrict__ W_ih0,  // [256,4]
    const float* __restrict__ W_ihr,  // [3,256,64]
    const float* __restrict__ W_hh,   // [4,256,64]
    const float* __restrict__ b_ih,   // [4,256]
    const float* __restrict__ b_hh,   // [4,256]
    const float* __restrict__ W_fc,   // [5,64]
    const float* __restrict__ b_fc,   // [5]
    float* __restrict__ out)          // [B,5]
{
    const int tid   = threadIdx.x;
    const int wave  = tid >> 6;       // 0..7
    const int layer = wave >> 1;      // 0..3
    const int j     = wave & 1;       // half within layer
    const int lane  = tid & 63;
    const int q     = lane >> 4;
    const int ln    = lane & 15;
    const int b0    = blockIdx.x * NB;

    // A-operand buffers: [layer][parity][hilo][m][kappa]; kappa<64 = own h
    // (phi-permuted), kappa in [64,128) = prev-layer h (phi) or x (layer 0).
    __shared__ f16 buf[4][2][2][NB][ROWE];       // 71.7 KB
    __shared__ float hf[NB][H_ + 1];             // FC staging

    // zero buf once (zero-padded x columns 68..128 of layer 0 + h(-1)=0)
    {
        f16* pz = &buf[0][0][0][0][0];
        const int tot = 4 * 2 * 2 * NB * ROWE;
        for (int i = tid; i < tot; i += 512) pz[i] = (f16)0.0f;
    }

    // ---- weights -> f16 B-fragments in registers, K-columns phi-permuted ----
    const float* Whh = W_hh + (size_t)layer * 256 * 64;
    const float* Wih = (layer == 0) ? W_ih0 : (W_ihr + (size_t)(layer - 1) * 256 * 64);

    f16x8 Wf[4][2][4];     // [gate][s][kt]
    float bias[4][2];
#pragma unroll
    for (int g = 0; g < 4; ++g) {
#pragma unroll
        for (int s = 0; s < 2; ++s) {
            const int u = (2 * j + s) * 16 + ln;
            const int n = g * 64 + u;
            bias[g][s] = b_ih[layer * 256 + n] + b_hh[layer * 256 + n];
#pragma unroll
            for (int kt = 0; kt < 4; ++kt) {
                f16x8 f;
#pragma unroll
                for (int jj = 0; jj < 8; ++jj) {
                    const int kap = kt * 32 + q * 8 + jj;
                    float wv;
                    if (kap < 64) {
                        const int k = ((kap & 3) << 4) | (kap >> 2);   // phi^-1
                        wv = Whh[n * 64 + k];
                    } else {
                        const int kk = kap - 64;
                        if (layer == 0) wv = (kk < 4) ? Wih[n * 4 + kk] : 0.0f;
                        else {
                            const int k = ((kk & 3) << 4) | (kk >> 2);
                            wv = Wih[n * 64 + k];
                        }
                    }
                    f[jj] = (f16)wv;
                }
                Wf[g][s][kt] = f;
            }
        }
    }

    float c[2][4] = {{0.f, 0.f, 0.f, 0.f}, {0.f, 0.f, 0.f, 0.f}};
    float h[2][4] = {{0.f, 0.f, 0.f, 0.f}, {0.f, 0.f, 0.f, 0.f}};

    // ---- x loader (wave 0; lane -> (batch xm, elem xe)) ----
    const int xm = lane >> 2, xe = lane & 3;
    float xA = 0.0f;
    if (wave == 0) {
        const float x0 = x[(size_t)(b0 + xm) * (T_ * 4) + xe];       // x(0)
        const f16 hh = (f16)x0;
        buf[0][0][0][xm][64 + xe] = hh;
        buf[0][0][1][xm][64 + xe] = (f16)(x0 - (float)hh);
        xA = x[(size_t)(b0 + xm) * (T_ * 4) + 4 + xe];               // x(1)
    }

#pragma unroll 1
    for (int i = 0; i < T_ + 3; ++i) {
        __syncthreads();                 // the ONLY barrier per iteration
        const int t = i - layer;
        if (t >= 0 && t < T_) {
            const int p = t & 1;

            // stage x(t+1) + prefetch x(t+2) (layer-0 wave 0 only)
            if (wave == 0) {
                if (t + 1 < T_) {
                    const f16 hh = (f16)xA;
                    buf[0][p ^ 1][0][xm][64 + xe] = hh;
                    buf[0][p ^ 1][1][xm][64 + xe] = (f16)(xA - (float)hh);
                }
                if (t + 2 < T_)
                    xA = x[(size_t)(b0 + xm) * (T_ * 4) + (t + 2) * 4 + xe];
            }

            // ---- MFMA: gates for 16 batches x own 8 gate-tiles ----
            f32x4 acc[4][2];
#pragma unroll
            for (int g = 0; g < 4; ++g)
#pragma unroll
                for (int s = 0; s < 2; ++s)
                    acc[g][s] = (f32x4){0.f, 0.f, 0.f, 0.f};

#pragma unroll
            for (int kt = 0; kt < 4; ++kt) {
                const f16x8 Ah = *(const f16x8*)&buf[layer][p][0][ln][kt * 32 + q * 8];
                const f16x8 Al = *(const f16x8*)&buf[layer][p][1][ln][kt * 32 + q * 8];
#pragma unroll
                for (int g = 0; g < 4; ++g) {
#pragma unroll
                    for (int s = 0; s < 2; ++s) {
                        acc[g][s] = __builtin_amdgcn_mfma_f32_16x16x32_f16(Ah, Wf[g][s][kt], acc[g][s], 0, 0, 0);
                        acc[g][s] = __builtin_amdgcn_mfma_f32_16x16x32_f16(Al, Wf[g][s][kt], acc[g][s], 0, 0, 0);
                    }
                }
            }

            // ---- pointwise (registers) + h staging to LDS ----
            const int pn = p ^ 1;
            const int col = 4 * ln + 2 * j;
#pragma unroll
            for (int r = 0; r < 4; ++r) {
                const int m = q * 4 + r;
                f16x2 hh2, hl2;
#pragma unroll
                for (int s = 0; s < 2; ++s) {
                    const float gi = acc[0][s][r] + bias[0][s];
                    const float gf = acc[1][s][r] + bias[1][s];
                    const float gg = acc[2][s][r] + bias[2][s];
                    const float go = acc[3][s][r] + bias[3][s];
                    c[s][r] = sigf(gf) * c[s][r] + sigf(gi) * tanh_fast(gg);
                    h[s][r] = sigf(go) * tanh_fast(c[s][r]);
                    const f16 hh = (f16)h[s][r];
                    hh2[s] = hh;
                    hl2[s] = (f16)(h[s][r] - (float)hh);
                }
                // own recurrence: consumed by self at step t+1 (parity pn)
                *(f16x2*)&buf[layer][pn][0][m][col] = hh2;
                *(f16x2*)&buf[layer][pn][1][m][col] = hl2;
                // next layer's input: consumed by layer+1 at ITS step t (parity p)
                if (layer < 3) {
                    *(f16x2*)&buf[layer + 1][p][0][m][64 + col] = hh2;
                    *(f16x2*)&buf[layer + 1][p][1][m][64 + col] = hl2;
                }
            }
        }
    }

    // ---- FC epilogue on h(T-1) of layer 3 ----
    if (layer == 3) {
#pragma unroll
        for (int s = 0; s < 2; ++s)
#pragma unroll
            for (int r = 0; r < 4; ++r)
                hf[q * 4 + r][(2 * j + s) * 16 + ln] = h[s][r];
    }
    __syncthreads();
    if (tid < NB * OUT_) {
        const int b = tid / OUT_, o = tid % OUT_;
        float a = b_fc[o];
#pragma unroll
        for (int k = 0; k < H_; ++k)
            a = fmaf(hf[b][k], W_fc[o * H_ + k], a);
        out[(b0 + b) * OUT_ + o] = a;
    }
}

extern "C" void kernel_launch(void* const* d_in, const int* in_sizes, int n_in,
                              void* d_out, int out_size, void* d_ws, size_t ws_size,
                              hipStream_t stream) {
    const float* x     = (const float*)d_in[0];
    const float* W_ih0 = (const float*)d_in[1];
    const float* W_ihr = (const float*)d_in[2];
    const float* W_hh  = (const float*)d_in[3];
    const float* b_ih  = (const float*)d_in[4];
    const float* b_hh  = (const float*)d_in[5];
    const float* W_fc  = (const float*)d_in[6];
    const float* b_fc  = (const float*)d_in[7];
    float* out = (float*)d_out;

    lstm_fused_k<<<dim3(B_ / NB), dim3(512), 0, stream>>>(
        x, W_ih0, W_ihr, W_hh, b_ih, b_hh, W_fc, b_fc, out);
}

// Round 6
// 1088.979 us; speedup vs baseline: 3.6245x; 1.1778x over previous
//
#include <hip/hip_runtime.h>

// Stacked LSTM B=2048,T=512,IN=4,H=64,L=4,OUT=5 — single-block layer pipeline v2.
// ONE kernel, grid 256 (ALL CUs; R5's grid 128 left half the chip idle), block
// 512 (8 waves). Wave pair (2l,2l+1) = layer l; 4 layers of an NB=8 batch
// group run in the same block with 1-step skew (iter i: layer l does t=i-l).
// Inter-layer h flows through LDS (double-buffered by parity), ONE
// __syncthreads per iteration. Critical path: T+3 = 515 iterations.
// Math: 16x16x32 f16 MFMA; weights single-plane f16 in registers (|W|<0.7,
// 11-bit mantissa); activations hi/lo f16 split (2 MFMAs). NB=8 < M=16:
// A-rows 8..15 stay zero; D rows are independent so garbage accs for m>=8
// are simply discarded. Pointwise: accs redistributed via __shfl_xor(32) so
// ALL 64 lanes do 4 h-updates (lane q>=2 adopts the s=1 work of lane q-2;
// c/h state lives permanently in the remapped lane). K-columns phi-permuted
// (phi(u)=4*(u&15)+(u>>4)) so a lane's h lands at one f16 column; weights
// permuted to match. FC fused at the end.

#define B_    2048
#define T_    512
#define H_    64
#define NB    8
#define OUT_  5
#define ROWE  140      // f16 elems per A-row (280B: bank-staggered, 8B aligned)

typedef _Float16 f16;
typedef __attribute__((ext_vector_type(8))) _Float16 f16x8;
typedef __attribute__((ext_vector_type(4))) float f32x4;

__device__ __forceinline__ float sigf(float x) {
    return __builtin_amdgcn_rcpf(1.0f + __expf(-x));
}
__device__ __forceinline__ float tanh_fast(float x) {
    return 1.0f - 2.0f * __builtin_amdgcn_rcpf(1.0f + __expf(2.0f * x));
}

__global__ __launch_bounds__(512, 2) void lstm_fused_k(
    const float* __restrict__ x,      // [B,T,4]
    const float* __restrict__ W_ih0,  // [256,4]
    const float* __restrict__ W_ihr,  // [3,256,64]
    const float* __restrict__ W_hh,   // [4,256,64]
    const float* __restrict__ b_ih,   // [4,256]
    const float* __restrict__ b_hh,   // [4,256]
    const float* __restrict__ W_fc,   // [5,64]
    const float* __restrict__ b_fc,   // [5]
    float* __restrict__ out)          // [B,5]
{
    const int tid   = threadIdx.x;
    const int wave  = tid >> 6;       // 0..7
    const int layer = wave >> 1;      // 0..3
    const int j     = wave & 1;       // half within layer
    const int lane  = tid & 63;
    const int q     = lane >> 4;
    const int ln    = lane & 15;
    const int b0    = blockIdx.x * NB;

    // [layer][parity][hilo][m(16; 8..15 always zero)][kappa]
    __shared__ f16 buf[4][2][2][16][ROWE];       // 71.7 KB
    __shared__ float hf[NB][H_ + 1];             // FC staging

    // zero buf once (rows 8..15, x-pad cols, h(-1))
    {
        f16* pz = &buf[0][0][0][0][0];
        const int tot = 4 * 2 * 2 * 16 * ROWE;
        for (int i = tid; i < tot; i += 512) pz[i] = (f16)0.0f;
    }

    // ---- weights -> f16 B-fragments in registers, K-columns phi-permuted ----
    const float* Whh = W_hh + (size_t)layer * 256 * 64;
    const float* Wih = (layer == 0) ? W_ih0 : (W_ihr + (size_t)(layer - 1) * 256 * 64);

    f16x8 Wf[4][2][4];     // [gate][s][kt]
    float bias[4][2];
#pragma unroll
    for (int g = 0; g < 4; ++g) {
#pragma unroll
        for (int s = 0; s < 2; ++s) {
            const int u = (2 * j + s) * 16 + ln;
            const int n = g * 64 + u;
            bias[g][s] = b_ih[layer * 256 + n] + b_hh[layer * 256 + n];
#pragma unroll
            for (int kt = 0; kt < 4; ++kt) {
                f16x8 f;
#pragma unroll
                for (int jj = 0; jj < 8; ++jj) {
                    const int kap = kt * 32 + q * 8 + jj;
                    float wv;
                    if (kap < 64) {
                        const int k = ((kap & 3) << 4) | (kap >> 2);   // phi^-1
                        wv = Whh[n * 64 + k];
                    } else {
                        const int kk = kap - 64;
                        if (layer == 0) wv = (kk < 4) ? Wih[n * 4 + kk] : 0.0f;
                        else {
                            const int k = ((kk & 3) << 4) | (kk >> 2);
                            wv = Wih[n * 64 + k];
                        }
                    }
                    f[jj] = (f16)wv;
                }
                Wf[g][s][kt] = f;
            }
        }
    }

    // ---- remapped pointwise assignment ----
    // lane (q,ln): s_my = q>>1, batches m = (q&1)*4 + r, unit u_my = (2j+s_my)*16+ln
    const int s_my   = q >> 1;
    const int m_base = (q & 1) * 4;
    const int col    = 4 * ln + 2 * j + s_my;     // phi(u_my)
    const float biasR[4] = {bias[0][s_my], bias[1][s_my], bias[2][s_my], bias[3][s_my]};

    float c[4]  = {0.f, 0.f, 0.f, 0.f};
    float hv[4] = {0.f, 0.f, 0.f, 0.f};

    // ---- x loader (wave 0, lanes 0..31: batch xm, elem xe) ----
    const int xm = lane >> 2, xe = lane & 3;
    float xA = 0.0f;
    if (wave == 0 && lane < 32) {
        const float x0 = x[(size_t)(b0 + xm) * (T_ * 4) + xe];       // x(0)
        const f16 hh = (f16)x0;
        buf[0][0][0][xm][64 + xe] = hh;
        buf[0][0][1][xm][64 + xe] = (f16)(x0 - (float)hh);
        xA = x[(size_t)(b0 + xm) * (T_ * 4) + 4 + xe];               // x(1)
    }

#pragma unroll 1
    for (int i = 0; i < T_ + 3; ++i) {
        __syncthreads();                 // the ONLY barrier per iteration
        const int t = i - layer;
        if (t >= 0 && t < T_) {
            const int p = t & 1;

            // stage x(t+1) + prefetch x(t+2) (layer-0 wave 0 only)
            if (wave == 0 && lane < 32) {
                if (t + 1 < T_) {
                    const f16 hh = (f16)xA;
                    buf[0][p ^ 1][0][xm][64 + xe] = hh;
                    buf[0][p ^ 1][1][xm][64 + xe] = (f16)(xA - (float)hh);
                }
                if (t + 2 < T_)
                    xA = x[(size_t)(b0 + xm) * (T_ * 4) + (t + 2) * 4 + xe];
            }

            // ---- MFMA: gates for 8 batches x own 8 gate-tiles ----
            f32x4 acc[4][2];
#pragma unroll
            for (int g = 0; g < 4; ++g)
#pragma unroll
                for (int s = 0; s < 2; ++s)
                    acc[g][s] = (f32x4){0.f, 0.f, 0.f, 0.f};

#pragma unroll
            for (int kt = 0; kt < 4; ++kt) {
                const f16x8 Ah = *(const f16x8*)&buf[layer][p][0][ln][kt * 32 + q * 8];
                const f16x8 Al = *(const f16x8*)&buf[layer][p][1][ln][kt * 32 + q * 8];
#pragma unroll
                for (int g = 0; g < 4; ++g) {
#pragma unroll
                    for (int s = 0; s < 2; ++s) {
                        acc[g][s] = __builtin_amdgcn_mfma_f32_16x16x32_f16(Ah, Wf[g][s][kt], acc[g][s], 0, 0, 0);
                        acc[g][s] = __builtin_amdgcn_mfma_f32_16x16x32_f16(Al, Wf[g][s][kt], acc[g][s], 0, 0, 0);
                    }
                }
            }

            // ---- redistribute accs so all 64 lanes have 4 real updates ----
            // lane<32 (s_my=0): local acc[g][0][r] is its work.
            // lane>=32 (s_my=1): partner lane-32 holds valid acc[g][1][r].
            float accR[4][4];
#pragma unroll
            for (int g = 0; g < 4; ++g)
#pragma unroll
                for (int r = 0; r < 4; ++r) {
                    const float other = __shfl_xor(acc[g][1][r], 32, 64);
                    accR[g][r] = (lane < 32) ? acc[g][0][r] : other;
                }

            // ---- pointwise + h staging ----
            const int pn = p ^ 1;
#pragma unroll
            for (int r = 0; r < 4; ++r) {
                const int m = m_base + r;
                const float gi = accR[0][r] + biasR[0];
                const float gf = accR[1][r] + biasR[1];
                const float gg = accR[2][r] + biasR[2];
                const float go = accR[3][r] + biasR[3];
                c[r]  = sigf(gf) * c[r] + sigf(gi) * tanh_fast(gg);
                hv[r] = sigf(go) * tanh_fast(c[r]);
                const f16 hh = (f16)hv[r];
                const f16 hl = (f16)(hv[r] - (float)hh);
                // own recurrence: consumed by self at step t+1 (parity pn)
                buf[layer][pn][0][m][col] = hh;
                buf[layer][pn][1][m][col] = hl;
                // next layer's input: consumed by layer+1 at ITS step t (parity p)
                if (layer < 3) {
                    buf[layer + 1][p][0][m][64 + col] = hh;
                    buf[layer + 1][p][1][m][64 + col] = hl;
                }
            }
        }
    }

    // ---- FC epilogue on h(T-1) of layer 3 ----
    if (layer == 3) {
#pragma unroll
        for (int r = 0; r < 4; ++r)
            hf[m_base + r][(2 * j + s_my) * 16 + ln] = hv[r];
    }
    __syncthreads();
    if (tid < NB * OUT_) {
        const int b = tid / OUT_, o = tid % OUT_;
        float a = b_fc[o];
#pragma unroll
        for (int k = 0; k < H_; ++k)
            a = fmaf(hf[b][k], W_fc[o * H_ + k], a);
        out[(b0 + b) * OUT_ + o] = a;
    }
}

extern "C" void kernel_launch(void* const* d_in, const int* in_sizes, int n_in,
                              void* d_out, int out_size, void* d_ws, size_t ws_size,
                              hipStream_t stream) {
    const float* x     = (const float*)d_in[0];
    const float* W_ih0 = (const float*)d_in[1];
    const float* W_ihr = (const float*)d_in[2];
    const float* W_hh  = (const float*)d_in[3];
    const float* b_ih  = (const float*)d_in[4];
    const float* b_hh  = (const float*)d_in[5];
    const float* W_fc  = (const float*)d_in[6];
    const float* b_fc  = (const float*)d_in[7];
    float* out = (float*)d_out;

    lstm_fused_k<<<dim3(B_ / NB), dim3(512), 0, stream>>>(
        x, W_ih0, W_ihr, W_hh, b_ih, b_hh, W_fc, b_fc, out);
}